// Round 2
// baseline (369.722 us; speedup 1.0000x reference)
//
#include <hip/hip_runtime.h>

#define HID 20
#define NLAY 7

struct SW {
    float WT[NLAY][HID][HID];  // [layer][out j][in i]  (transposed for column reads)
    float Bh[NLAY][HID];
    float WTin[HID][4];        // [j][k], k=0..2
    float Bin[HID];
    float Wout[HID][2];
};

__device__ __forceinline__ void stage_weights(SW& s,
    const float* __restrict__ W_in, const float* __restrict__ b_in,
    const float* __restrict__ W_hid, const float* __restrict__ b_hid,
    const float* __restrict__ W_out)
{
    const int t = threadIdx.x, bs = blockDim.x;
    for (int f = t; f < NLAY * HID * HID; f += bs) {
        const int l = f / (HID * HID), r = f % (HID * HID);
        const int i = r / HID, j = r % HID;
        s.WT[l][j][i] = W_hid[f];
    }
    for (int f = t; f < NLAY * HID; f += bs) s.Bh[f / HID][f % HID] = b_hid[f];
    for (int f = t; f < 3 * HID; f += bs) { const int k = f / HID, j = f % HID; s.WTin[j][k] = W_in[f]; }
    for (int f = t; f < HID; f += bs) s.Bin[f] = b_in[f];
    for (int f = t; f < 2 * HID; f += bs) s.Wout[f / 2][f & 1] = W_out[f];
}

__device__ __forceinline__ float tanh_derivs(float a, float& d1, float& d2, float& d3) {
    const float e = __expf(2.0f * a);
    const float sg = 1.0f - __fdividef(2.0f, e + 1.0f);
    d1 = 1.0f - sg * sg;
    d2 = -2.0f * sg * d1;
    d3 = -2.0f * (d1 * d1 + sg * d2);
    return sg;
}

#define LOADCOL(dst, l, j) do {                                    \
    const float4* c_ = (const float4*)&s.WT[(l)][(j)][0];          \
    *(float4*)&dst[0]  = c_[0];  *(float4*)&dst[4]  = c_[1];       \
    *(float4*)&dst[8]  = c_[2];  *(float4*)&dst[12] = c_[3];       \
    *(float4*)&dst[16] = c_[4]; } while (0)

// ---------------- Phase A: spatial jet {val,gx,gy,hxx,hxy,hyy,Lx,Ly} ----------------

__device__ __forceinline__ void colA(const float* __restrict__ w,
                                     const float (*__restrict__ h)[8],
                                     float* __restrict__ hn, float bias)
{
    float acc[8];
    acc[0] = bias;
    #pragma unroll
    for (int c = 1; c < 8; ++c) acc[c] = 0.0f;
    #pragma unroll
    for (int i = 0; i < HID; ++i) {
        #pragma unroll
        for (int c = 0; c < 8; ++c) acc[c] = fmaf(w[i], h[i][c], acc[c]);
    }
    float d1, d2, d3;
    const float sg = tanh_derivs(acc[0], d1, d2, d3);
    const float gx = acc[1], gy = acc[2];
    const float hxx = acc[3], hxy = acc[4], hyy = acc[5];
    const float g2 = gx * gx + gy * gy;
    hn[0] = sg;
    hn[1] = d1 * gx;
    hn[2] = d1 * gy;
    hn[3] = fmaf(d2, gx * gx, d1 * hxx);
    hn[4] = fmaf(d2, gx * gy, d1 * hxy);
    hn[5] = fmaf(d2, gy * gy, d1 * hyy);
    hn[6] = d3 * gx * g2 + d2 * (3.0f * gx * hxx + 2.0f * gy * hxy + gx * hyy) + d1 * acc[6];
    hn[7] = d3 * gy * g2 + d2 * (3.0f * gy * hyy + 2.0f * gx * hxy + gy * hxx) + d1 * acc[7];
}

__global__ void __launch_bounds__(256, 1)
pinnA(const float* __restrict__ xs, const float* __restrict__ ys, const float* __restrict__ ts,
      const float* __restrict__ W_in, const float* __restrict__ b_in,
      const float* __restrict__ W_hid, const float* __restrict__ b_hid,
      const float* __restrict__ W_out, const float* __restrict__ b_out,
      const float* __restrict__ lam1p, const float* __restrict__ lam2p,
      float* __restrict__ out, int N)
{
    __shared__ SW s;
    stage_weights(s, W_in, b_in, W_hid, b_hid, W_out);
    __syncthreads();

    const int idx = blockIdx.x * blockDim.x + threadIdx.x;
    if (idx >= N) return;
    const float xv = xs[idx], yv = ys[idx], tv = ts[idx];
    const float l1 = lam1p[0], l2 = lam2p[0];

    float h[HID][8];
    #pragma unroll
    for (int j = 0; j < HID; ++j) {
        const float w0 = s.WTin[j][0], w1 = s.WTin[j][1], w2 = s.WTin[j][2];
        const float a0 = fmaf(xv, w0, fmaf(yv, w1, fmaf(tv, w2, s.Bin[j])));
        float d1, d2, d3;
        const float sg = tanh_derivs(a0, d1, d2, d3);
        const float g2 = w0 * w0 + w1 * w1;
        h[j][0] = sg;
        h[j][1] = d1 * w0;
        h[j][2] = d1 * w1;
        h[j][3] = d2 * w0 * w0;
        h[j][4] = d2 * w0 * w1;
        h[j][5] = d2 * w1 * w1;
        h[j][6] = d3 * w0 * g2;
        h[j][7] = d3 * w1 * g2;
    }

    #pragma unroll 1
    for (int l = 0; l < NLAY; ++l) {
        float hn[HID][8];
        float wA[HID], wB[HID];
        LOADCOL(wA, l, 0);
        #pragma unroll 1
        for (int j2 = 0; j2 < HID; j2 += 2) {
            LOADCOL(wB, l, j2 + 1);
            colA(wA, h, hn[j2], s.Bh[l][j2]);
            const int jn = (j2 + 2 < HID) ? (j2 + 2) : 0;
            LOADCOL(wA, l, jn);
            colA(wB, h, hn[j2 + 1], s.Bh[l][j2 + 1]);
        }
        #pragma unroll
        for (int j = 0; j < HID; ++j) {
            #pragma unroll
            for (int c = 0; c < 8; ++c) h[j][c] = hn[j][c];
        }
    }

    float psi1 = 0, psi2 = 0, psi3 = 0, psi4 = 0, psi5 = 0, psi6 = 0, psi7 = 0;
    float pr0 = 0, pr1 = 0, pr2 = 0;
    #pragma unroll
    for (int i = 0; i < HID; ++i) {
        const float w0 = s.Wout[i][0], w1 = s.Wout[i][1];
        psi1 = fmaf(w0, h[i][1], psi1);
        psi2 = fmaf(w0, h[i][2], psi2);
        psi3 = fmaf(w0, h[i][3], psi3);
        psi4 = fmaf(w0, h[i][4], psi4);
        psi5 = fmaf(w0, h[i][5], psi5);
        psi6 = fmaf(w0, h[i][6], psi6);
        psi7 = fmaf(w0, h[i][7], psi7);
        pr0  = fmaf(w1, h[i][0], pr0);
        pr1  = fmaf(w1, h[i][1], pr1);
        pr2  = fmaf(w1, h[i][2], pr2);
    }
    const float u = psi2, v = -psi1, p = pr0 + b_out[1];
    const float ux = psi4, uy = psi5, vx = -psi3, vy = -psi4;
    const float px = pr1, py = pr2, lx = psi6, ly = psi7;

    const float fuP = l1 * (u * ux + v * uy) + px - l2 * ly;
    const float fvP = l1 * (u * vx + v * vy) + py + l2 * lx;

    out[idx]         = u;
    out[N + idx]     = v;
    out[2 * N + idx] = p;
    out[3 * N + idx] = fuP;
    out[4 * N + idx] = fvP;
}

// ---------------- Phase B: time jet {val,gx,gy,gt,hxt,hyt} ----------------

__device__ __forceinline__ void colB(const float* __restrict__ w,
                                     const float (*__restrict__ h)[6],
                                     float* __restrict__ hn, float bias)
{
    float acc[6];
    acc[0] = bias;
    #pragma unroll
    for (int c = 1; c < 6; ++c) acc[c] = 0.0f;
    #pragma unroll
    for (int i = 0; i < HID; ++i) {
        #pragma unroll
        for (int c = 0; c < 6; ++c) acc[c] = fmaf(w[i], h[i][c], acc[c]);
    }
    float d1, d2, d3;
    const float sg = tanh_derivs(acc[0], d1, d2, d3);
    hn[0] = sg;
    hn[1] = d1 * acc[1];
    hn[2] = d1 * acc[2];
    hn[3] = d1 * acc[3];
    hn[4] = fmaf(d2, acc[1] * acc[3], d1 * acc[4]);
    hn[5] = fmaf(d2, acc[2] * acc[3], d1 * acc[5]);
}

__global__ void __launch_bounds__(256, 2)
pinnB(const float* __restrict__ xs, const float* __restrict__ ys, const float* __restrict__ ts,
      const float* __restrict__ W_in, const float* __restrict__ b_in,
      const float* __restrict__ W_hid, const float* __restrict__ b_hid,
      const float* __restrict__ W_out,
      float* __restrict__ out, int N)
{
    __shared__ SW s;
    stage_weights(s, W_in, b_in, W_hid, b_hid, W_out);
    __syncthreads();

    const int idx = blockIdx.x * blockDim.x + threadIdx.x;
    if (idx >= N) return;
    const float xv = xs[idx], yv = ys[idx], tv = ts[idx];

    float h[HID][6];
    #pragma unroll
    for (int j = 0; j < HID; ++j) {
        const float w0 = s.WTin[j][0], w1 = s.WTin[j][1], w2 = s.WTin[j][2];
        const float a0 = fmaf(xv, w0, fmaf(yv, w1, fmaf(tv, w2, s.Bin[j])));
        float d1, d2, d3;
        const float sg = tanh_derivs(a0, d1, d2, d3);
        h[j][0] = sg;
        h[j][1] = d1 * w0;
        h[j][2] = d1 * w1;
        h[j][3] = d1 * w2;
        h[j][4] = d2 * w0 * w2;
        h[j][5] = d2 * w1 * w2;
    }

    #pragma unroll 1
    for (int l = 0; l < NLAY; ++l) {
        float hn[HID][6];
        float wA[HID], wB[HID];
        LOADCOL(wA, l, 0);
        #pragma unroll 1
        for (int j2 = 0; j2 < HID; j2 += 2) {
            LOADCOL(wB, l, j2 + 1);
            colB(wA, h, hn[j2], s.Bh[l][j2]);
            const int jn = (j2 + 2 < HID) ? (j2 + 2) : 0;
            LOADCOL(wA, l, jn);
            colB(wB, h, hn[j2 + 1], s.Bh[l][j2 + 1]);
        }
        #pragma unroll
        for (int j = 0; j < HID; ++j) {
            #pragma unroll
            for (int c = 0; c < 6; ++c) h[j][c] = hn[j][c];
        }
    }

    float pxt = 0.0f, pyt = 0.0f;
    #pragma unroll
    for (int i = 0; i < HID; ++i) {
        const float w0 = s.Wout[i][0];
        pxt = fmaf(w0, h[i][4], pxt);
        pyt = fmaf(w0, h[i][5], pyt);
    }
    const float ut = pyt, vt = -pxt;

    out[3 * N + idx] += ut;
    out[4 * N + idx] += vt;
}

extern "C" void kernel_launch(void* const* d_in, const int* in_sizes, int n_in,
                              void* d_out, int out_size, void* d_ws, size_t ws_size,
                              hipStream_t stream) {
    const float* xs    = (const float*)d_in[0];
    const float* ys    = (const float*)d_in[1];
    const float* ts    = (const float*)d_in[2];
    const float* W_in  = (const float*)d_in[3];
    const float* b_in  = (const float*)d_in[4];
    const float* W_hid = (const float*)d_in[5];
    const float* b_hid = (const float*)d_in[6];
    const float* W_out = (const float*)d_in[7];
    const float* b_out = (const float*)d_in[8];
    const float* lam1  = (const float*)d_in[9];
    const float* lam2  = (const float*)d_in[10];
    float* out = (float*)d_out;

    const int N = in_sizes[0];
    const int block = 256;
    const int grid = (N + block - 1) / block;
    pinnA<<<grid, block, 0, stream>>>(xs, ys, ts, W_in, b_in, W_hid, b_hid,
                                      W_out, b_out, lam1, lam2, out, N);
    pinnB<<<grid, block, 0, stream>>>(xs, ys, ts, W_in, b_in, W_hid, b_hid,
                                      W_out, out, N);
}

// Round 3
// 314.324 us; speedup vs baseline: 1.1762x; 1.1762x over previous
//
#include <hip/hip_runtime.h>

#define HID 20
#define NLAY 7

typedef float v2f __attribute__((ext_vector_type(2)));

__device__ __forceinline__ v2f vfma(v2f a, v2f b, v2f c) {
    return __builtin_elementwise_fma(a, b, c);
}

// tanh and its first three derivatives, via one hardware exp.
__device__ __forceinline__ float tanh_derivs(float a, float& d1, float& d2, float& d3) {
    const float e = __expf(2.0f * a);
    const float s = 1.0f - __fdividef(2.0f, e + 1.0f);
    d1 = 1.0f - s * s;               // f'
    d2 = -2.0f * s * d1;             // f''
    d3 = -2.0f * (d1 * d1 + s * d2); // f'''
    return s;
}

__global__ void __launch_bounds__(256, 1)
pinn_kernel(const float* __restrict__ xs, const float* __restrict__ ys, const float* __restrict__ ts,
            const float* __restrict__ W_in, const float* __restrict__ b_in,
            const float* __restrict__ W_hid, const float* __restrict__ b_hid,
            const float* __restrict__ W_out, const float* __restrict__ b_out,
            const float* __restrict__ lam1p, const float* __restrict__ lam2p,
            float* __restrict__ out, int N)
{
    const int idx = blockIdx.x * blockDim.x + threadIdx.x;
    if (idx >= N) return;
    const float xv = xs[idx], yv = ys[idx], tv = ts[idx];
    const float l1 = lam1p[0], l2 = lam2p[0];

    float u, v, p, ux, uy, vx, vy, px, py, lx, ly;

    // ================= Phase A =================
    // comps: 0=val 1=gx 2=gy 3=hxx 4=hxy 5=hyy 6=Lx 7=Ly
    // pairs: h[j][0]=(val,gx) h[j][1]=(gy,hxx) h[j][2]=(hxy,hyy) h[j][3]=(Lx,Ly)
    {
        v2f h[HID][4];
        #pragma unroll
        for (int j = 0; j < HID; ++j) {
            const float w0 = W_in[j], w1 = W_in[HID + j], w2 = W_in[2 * HID + j];
            const float a0 = fmaf(xv, w0, fmaf(yv, w1, fmaf(tv, w2, b_in[j])));
            float d1, d2, d3;
            const float s = tanh_derivs(a0, d1, d2, d3);
            const float g2 = w0 * w0 + w1 * w1;
            h[j][0] = (v2f){s, d1 * w0};
            h[j][1] = (v2f){d1 * w1, d2 * w0 * w0};
            h[j][2] = (v2f){d2 * w0 * w1, d2 * w1 * w1};
            h[j][3] = (v2f){d3 * w0 * g2, d3 * w1 * g2};
        }
        #pragma unroll 1
        for (int l = 0; l < NLAY; ++l) {
            const float* __restrict__ Wl = W_hid + l * HID * HID;
            const float* __restrict__ bl = b_hid + l * HID;
            v2f acc[HID][4];
            #pragma unroll
            for (int j = 0; j < HID; ++j) {
                acc[j][0] = (v2f){bl[j], 0.0f};
                acc[j][1] = (v2f){0.0f, 0.0f};
                acc[j][2] = (v2f){0.0f, 0.0f};
                acc[j][3] = (v2f){0.0f, 0.0f};
            }
            #pragma unroll
            for (int i = 0; i < HID; ++i) {
                #pragma unroll
                for (int j = 0; j < HID; ++j) {
                    const float w = Wl[i * HID + j];
                    const v2f ww = (v2f){w, w};
                    #pragma unroll
                    for (int q = 0; q < 4; ++q) acc[j][q] = vfma(ww, h[i][q], acc[j][q]);
                }
            }
            #pragma unroll
            for (int j = 0; j < HID; ++j) {
                float d1, d2, d3;
                const float s   = tanh_derivs(acc[j][0].x, d1, d2, d3);
                const float gx  = acc[j][0].y, gy = acc[j][1].x;
                const float hxx = acc[j][1].y, hxy = acc[j][2].x, hyy = acc[j][2].y;
                const float g2 = gx * gx + gy * gy;
                const float nLx = d3 * gx * g2 + d2 * (3.0f * gx * hxx + 2.0f * gy * hxy + gx * hyy) + d1 * acc[j][3].x;
                const float nLy = d3 * gy * g2 + d2 * (3.0f * gy * hyy + 2.0f * gx * hxy + gy * hxx) + d1 * acc[j][3].y;
                h[j][0] = (v2f){s, d1 * gx};
                h[j][1] = (v2f){d1 * gy, fmaf(d2, gx * gx, d1 * hxx)};
                h[j][2] = (v2f){fmaf(d2, gx * gy, d1 * hxy), fmaf(d2, gy * gy, d1 * hyy)};
                h[j][3] = (v2f){nLx, nLy};
            }
        }
        // output layer: psi = col 0, p = col 1
        v2f psi0 = (v2f){0, 0}, psi1 = (v2f){0, 0}, psi2 = (v2f){0, 0}, psi3 = (v2f){0, 0};
        float p0 = 0, p1 = 0, p2 = 0;
        #pragma unroll
        for (int i = 0; i < HID; ++i) {
            const float w0 = W_out[2 * i], w1 = W_out[2 * i + 1];
            const v2f w00 = (v2f){w0, w0};
            psi0 = vfma(w00, h[i][0], psi0);
            psi1 = vfma(w00, h[i][1], psi1);
            psi2 = vfma(w00, h[i][2], psi2);
            psi3 = vfma(w00, h[i][3], psi3);
            p0 = fmaf(w1, h[i][0].x, p0);
            p1 = fmaf(w1, h[i][0].y, p1);
            p2 = fmaf(w1, h[i][1].x, p2);
        }
        u  = psi1.x;            // psi_y
        v  = -psi0.y;           // -psi_x
        p  = p0 + b_out[1];
        ux = psi2.x;            // psi_yx (hxy)
        uy = psi2.y;            // psi_yy (hyy)
        vx = -psi1.y;           // -psi_xx (hxx)
        vy = -psi2.x;           // -psi_xy
        px = p1; py = p2;
        lx = psi3.x;            // psi_xxx + psi_xyy
        ly = psi3.y;            // psi_xxy + psi_yyy
    }

    // ================= Phase B =================
    // comps: 0=val 1=gx 2=gy 3=gt 4=hxt 5=hyt
    // pairs: h[j][0]=(val,gx) h[j][1]=(gy,gt) h[j][2]=(hxt,hyt)
    float ut, vt;
    {
        v2f h[HID][3];
        #pragma unroll
        for (int j = 0; j < HID; ++j) {
            const float w0 = W_in[j], w1 = W_in[HID + j], w2 = W_in[2 * HID + j];
            const float a0 = fmaf(xv, w0, fmaf(yv, w1, fmaf(tv, w2, b_in[j])));
            float d1, d2, d3;
            const float s = tanh_derivs(a0, d1, d2, d3);
            h[j][0] = (v2f){s, d1 * w0};
            h[j][1] = (v2f){d1 * w1, d1 * w2};
            h[j][2] = (v2f){d2 * w0 * w2, d2 * w1 * w2};
        }
        #pragma unroll 1
        for (int l = 0; l < NLAY; ++l) {
            const float* __restrict__ Wl = W_hid + l * HID * HID;
            const float* __restrict__ bl = b_hid + l * HID;
            v2f acc[HID][3];
            #pragma unroll
            for (int j = 0; j < HID; ++j) {
                acc[j][0] = (v2f){bl[j], 0.0f};
                acc[j][1] = (v2f){0.0f, 0.0f};
                acc[j][2] = (v2f){0.0f, 0.0f};
            }
            #pragma unroll
            for (int i = 0; i < HID; ++i) {
                #pragma unroll
                for (int j = 0; j < HID; ++j) {
                    const float w = Wl[i * HID + j];
                    const v2f ww = (v2f){w, w};
                    #pragma unroll
                    for (int q = 0; q < 3; ++q) acc[j][q] = vfma(ww, h[i][q], acc[j][q]);
                }
            }
            #pragma unroll
            for (int j = 0; j < HID; ++j) {
                float d1, d2, d3;
                const float s  = tanh_derivs(acc[j][0].x, d1, d2, d3);
                const float gx = acc[j][0].y, gy = acc[j][1].x, gt = acc[j][1].y;
                h[j][0] = (v2f){s, d1 * gx};
                h[j][1] = (v2f){d1 * gy, d1 * gt};
                h[j][2] = (v2f){fmaf(d2, gx * gt, d1 * acc[j][2].x),
                                fmaf(d2, gy * gt, d1 * acc[j][2].y)};
            }
        }
        v2f pt = (v2f){0, 0};
        #pragma unroll
        for (int i = 0; i < HID; ++i) {
            const float w0 = W_out[2 * i];
            pt = vfma((v2f){w0, w0}, h[i][2], pt);
        }
        ut = pt.y;      // psi_yt
        vt = -pt.x;     // -psi_xt
    }

    const float fu = ut + l1 * (u * ux + v * uy) + px - l2 * ly;
    const float fv = vt + l1 * (u * vx + v * vy) + py + l2 * lx;

    out[idx]         = u;
    out[N + idx]     = v;
    out[2 * N + idx] = p;
    out[3 * N + idx] = fu;
    out[4 * N + idx] = fv;
}

extern "C" void kernel_launch(void* const* d_in, const int* in_sizes, int n_in,
                              void* d_out, int out_size, void* d_ws, size_t ws_size,
                              hipStream_t stream) {
    const float* xs    = (const float*)d_in[0];
    const float* ys    = (const float*)d_in[1];
    const float* ts    = (const float*)d_in[2];
    const float* W_in  = (const float*)d_in[3];
    const float* b_in  = (const float*)d_in[4];
    const float* W_hid = (const float*)d_in[5];
    const float* b_hid = (const float*)d_in[6];
    const float* W_out = (const float*)d_in[7];
    const float* b_out = (const float*)d_in[8];
    const float* lam1  = (const float*)d_in[9];
    const float* lam2  = (const float*)d_in[10];
    float* out = (float*)d_out;

    const int N = in_sizes[0];
    const int block = 256;
    const int grid = (N + block - 1) / block;
    pinn_kernel<<<grid, block, 0, stream>>>(xs, ys, ts, W_in, b_in, W_hid, b_hid,
                                            W_out, b_out, lam1, lam2, out, N);
}

// Round 4
// 191.735 us; speedup vs baseline: 1.9283x; 1.6394x over previous
//
#include <hip/hip_runtime.h>

#define HID 20
#define NLAY 7

typedef float v2f __attribute__((ext_vector_type(2)));

__device__ __forceinline__ v2f vfma(v2f a, v2f b, v2f c) {
    return __builtin_elementwise_fma(a, b, c);
}

// tanh and its first three derivatives, via one hardware exp.
__device__ __forceinline__ float tanh_derivs(float a, float& d1, float& d2, float& d3) {
    const float e = __expf(2.0f * a);
    const float s = 1.0f - __fdividef(2.0f, e + 1.0f);
    d1 = 1.0f - s * s;               // f'
    d2 = -2.0f * s * d1;             // f''
    d3 = -2.0f * (d1 * d1 + s * d2); // f'''
    return s;
}

// Single 11-component jet per point:
// pairs: q0=(val,gt) q1=(gx,gy) q2=(hxx,hyy) q3=(hxt,hyt) q4=(Lx,Ly), scalar: hxy
// where Lx = psi_xxx + psi_xyy, Ly = psi_xxy + psi_yyy.
__global__ void __launch_bounds__(256, 1)
pinn_kernel(const float* __restrict__ xs, const float* __restrict__ ys, const float* __restrict__ ts,
            const float* __restrict__ W_in, const float* __restrict__ b_in,
            const float* __restrict__ W_hid, const float* __restrict__ b_hid,
            const float* __restrict__ W_out, const float* __restrict__ b_out,
            const float* __restrict__ lam1p, const float* __restrict__ lam2p,
            float* __restrict__ out, int N)
{
    const int idx = blockIdx.x * blockDim.x + threadIdx.x;
    if (idx >= N) return;
    const float xv = xs[idx], yv = ys[idx], tv = ts[idx];
    const float l1 = lam1p[0], l2 = lam2p[0];

    v2f h[HID][5];
    float hxy[HID];

    // ---- input layer: a = w0*x + w1*y + w2*t + b ----
    #pragma unroll
    for (int j = 0; j < HID; ++j) {
        const float w0 = W_in[j], w1 = W_in[HID + j], w2 = W_in[2 * HID + j];
        const float a0 = fmaf(xv, w0, fmaf(yv, w1, fmaf(tv, w2, b_in[j])));
        float d1, d2, d3;
        const float s = tanh_derivs(a0, d1, d2, d3);
        const float g2w = w0 * w0 + w1 * w1;
        h[j][0] = (v2f){s, d1 * w2};
        h[j][1] = (v2f){d1 * w0, d1 * w1};
        h[j][2] = (v2f){d2 * w0 * w0, d2 * w1 * w1};
        h[j][3] = (v2f){d2 * w0 * w2, d2 * w1 * w2};
        h[j][4] = (v2f){d3 * w0 * g2w, d3 * w1 * g2w};
        hxy[j] = d2 * w0 * w1;
    }

    // ---- hidden layers ----
    #pragma unroll 1
    for (int l = 0; l < NLAY; ++l) {
        const float* __restrict__ Wl = W_hid + l * HID * HID;
        const float* __restrict__ bl = b_hid + l * HID;
        v2f acc[HID][5];
        float accxy[HID];
        #pragma unroll
        for (int j = 0; j < HID; ++j) {
            acc[j][0] = (v2f){bl[j], 0.0f};
            acc[j][1] = (v2f){0.0f, 0.0f};
            acc[j][2] = (v2f){0.0f, 0.0f};
            acc[j][3] = (v2f){0.0f, 0.0f};
            acc[j][4] = (v2f){0.0f, 0.0f};
            accxy[j] = 0.0f;
        }
        #pragma unroll
        for (int i = 0; i < HID; ++i) {
            #pragma unroll
            for (int j = 0; j < HID; ++j) {
                const float w = Wl[i * HID + j];
                const v2f ww = (v2f){w, w};
                #pragma unroll
                for (int q = 0; q < 5; ++q) acc[j][q] = vfma(ww, h[i][q], acc[j][q]);
                accxy[j] = fmaf(w, hxy[i], accxy[j]);
            }
        }
        #pragma unroll
        for (int j = 0; j < HID; ++j) {
            float d1, d2, d3;
            const float s   = tanh_derivs(acc[j][0].x, d1, d2, d3);
            const float agt = acc[j][0].y;
            const float agx = acc[j][1].x, agy = acc[j][1].y;
            const float ahxx = acc[j][2].x, ahyy = acc[j][2].y;
            const float ahxt = acc[j][3].x, ahyt = acc[j][3].y;
            const float aLx = acc[j][4].x, aLy = acc[j][4].y;
            const float ahxy = accxy[j];
            const float g2 = agx * agx + agy * agy;
            h[j][0] = (v2f){s, d1 * agt};
            h[j][1] = (v2f){d1 * agx, d1 * agy};
            h[j][2] = (v2f){fmaf(d2, agx * agx, d1 * ahxx),
                            fmaf(d2, agy * agy, d1 * ahyy)};
            h[j][3] = (v2f){fmaf(d2, agx * agt, d1 * ahxt),
                            fmaf(d2, agy * agt, d1 * ahyt)};
            h[j][4] = (v2f){d3 * agx * g2 + d2 * (3.0f * agx * ahxx + 2.0f * agy * ahxy + agx * ahyy) + d1 * aLx,
                            d3 * agy * g2 + d2 * (3.0f * agy * ahyy + 2.0f * agx * ahxy + agy * ahxx) + d1 * aLy};
            hxy[j] = fmaf(d2, agx * agy, d1 * ahxy);
        }
    }

    // ---- output layer: psi = col 0, p = col 1 ----
    v2f ps0 = (v2f){0, 0}, ps1 = (v2f){0, 0}, ps2 = (v2f){0, 0}, ps3 = (v2f){0, 0}, ps4 = (v2f){0, 0};
    float psxy = 0.0f;
    float pv = 0.0f;
    v2f pg = (v2f){0, 0};
    #pragma unroll
    for (int i = 0; i < HID; ++i) {
        const float w0 = W_out[2 * i], w1 = W_out[2 * i + 1];
        const v2f w00 = (v2f){w0, w0};
        ps0 = vfma(w00, h[i][0], ps0);
        ps1 = vfma(w00, h[i][1], ps1);
        ps2 = vfma(w00, h[i][2], ps2);
        ps3 = vfma(w00, h[i][3], ps3);
        ps4 = vfma(w00, h[i][4], ps4);
        psxy = fmaf(w0, hxy[i], psxy);
        pv   = fmaf(w1, h[i][0].x, pv);
        pg   = vfma((v2f){w1, w1}, h[i][1], pg);
    }

    const float u = ps1.y;          // psi_y
    const float v = -ps1.x;         // -psi_x
    const float p = pv + b_out[1];
    const float ux = psxy;          // psi_yx
    const float uy = ps2.y;         // psi_yy
    const float vx = -ps2.x;        // -psi_xx
    const float vy = -psxy;         // -psi_xy
    const float px = pg.x, py = pg.y;
    const float lx = ps4.x, ly = ps4.y;
    const float ut = ps3.y;         // psi_yt
    const float vt = -ps3.x;        // -psi_xt

    const float fu = ut + l1 * (u * ux + v * uy) + px - l2 * ly;
    const float fv = vt + l1 * (u * vx + v * vy) + py + l2 * lx;

    out[idx]         = u;
    out[N + idx]     = v;
    out[2 * N + idx] = p;
    out[3 * N + idx] = fu;
    out[4 * N + idx] = fv;
}

extern "C" void kernel_launch(void* const* d_in, const int* in_sizes, int n_in,
                              void* d_out, int out_size, void* d_ws, size_t ws_size,
                              hipStream_t stream) {
    const float* xs    = (const float*)d_in[0];
    const float* ys    = (const float*)d_in[1];
    const float* ts    = (const float*)d_in[2];
    const float* W_in  = (const float*)d_in[3];
    const float* b_in  = (const float*)d_in[4];
    const float* W_hid = (const float*)d_in[5];
    const float* b_hid = (const float*)d_in[6];
    const float* W_out = (const float*)d_in[7];
    const float* b_out = (const float*)d_in[8];
    const float* lam1  = (const float*)d_in[9];
    const float* lam2  = (const float*)d_in[10];
    float* out = (float*)d_out;

    const int N = in_sizes[0];
    const int block = 256;
    const int grid = (N + block - 1) / block;
    pinn_kernel<<<grid, block, 0, stream>>>(xs, ys, ts, W_in, b_in, W_hid, b_hid,
                                            W_out, b_out, lam1, lam2, out, N);
}